// Round 16
// baseline (238.902 us; speedup 1.0000x reference)
//
#include <hip/hip_runtime.h>

// LIF neuron scan over time (dim 0) + in-graph A/B probes.
//
// Standing facts (R1/R4/R6/R12/R14): correct scan kernel pinned at 62-65us,
// ~2.45 TB/s combined HBM, VALUBusy ~5%, MfmaUtil 0, insensitive to MLP
// structure, NT stores, grid shape; worse with fewer waves. All single-kernel
// theories eliminated. This round: per-dispatch A/B probes in one graph.
//   1) zz_probe_flat_copy  - flat 103MB float4 copy (canonical 6.3 TB/s shape)
//   2) zz_probe_8stream_copy - copy in the LIF 16-stream pattern, no scan dep
//   3) lif_kernel          - correct scan, LAST so d_out is correct.
// Decision: flat fast + 8stream fast -> scan serialization is the limiter.
//           flat fast + 8stream slow -> stream pattern is the HW limiter.
//           both slow -> ~2.45 TB/s is the machine ceiling here (roofline).
// R15: broker timeout, no data. Identical resubmit.

#pragma clang fp contract(off)

constexpr int   LIF_T     = 8;
constexpr float LIF_DECAY = 0.25f;

// ---------------- probe 1: flat contiguous copy ----------------
__global__ __launch_bounds__(256) void
zz_probe_flat_copy(const float4* __restrict__ src, float4* __restrict__ dst,
                   int nchunks)
{
    const int tid    = blockIdx.x * blockDim.x + threadIdx.x;
    const int stride = gridDim.x * blockDim.x;
    for (int i = tid; i < nchunks; i += stride)
        dst[i] = src[i];
}

// ---------------- probe 2: 16-stream copy (LIF pattern, no scan dep) -------
__global__ __launch_bounds__(256) void
zz_probe_8stream_copy(const float4* __restrict__ src, float4* __restrict__ dst,
                      int n4)
{
    const int i = blockIdx.x * blockDim.x + threadIdx.x;
    if (i >= n4) return;
    #pragma unroll
    for (int t = 0; t < LIF_T; ++t)
        dst[t * n4 + i] = src[t * n4 + i];
}

// ---------------- correct LIF scan (runs last) ----------------
__device__ __forceinline__ float lif_q4(float m)
{
    #pragma clang fp contract(off)
    return rintf(fminf(fmaxf(m, 0.f), 4.f));
}

__global__ __launch_bounds__(256) void
lif_kernel(const float4* __restrict__ x, float4* __restrict__ out, int n4)
{
    #pragma clang fp contract(off)

    const int i = blockIdx.x * blockDim.x + threadIdx.x;
    if (i >= n4) return;

    float mx = 0.f, my = 0.f, mz = 0.f, mw = 0.f;
    float sx = 0.f, sy = 0.f, sz = 0.f, sw = 0.f;

    #pragma unroll
    for (int t = 0; t < LIF_T; ++t) {
        const float4 xv = x[t * n4 + i];

        mx = (mx - sx) * LIF_DECAY + xv.x;
        my = (my - sy) * LIF_DECAY + xv.y;
        mz = (mz - sz) * LIF_DECAY + xv.z;
        mw = (mw - sw) * LIF_DECAY + xv.w;

        sx = lif_q4(mx);
        sy = lif_q4(my);
        sz = lif_q4(mz);
        sw = lif_q4(mw);

        out[t * n4 + i] = make_float4(sx, sy, sz, sw);
    }
}

// Scalar fallback (n_per_t % 4 != 0; not expected for this shape).
__global__ void
lif_kernel_tail(const float* __restrict__ x, float* __restrict__ out,
                int n_per_t, int start)
{
    #pragma clang fp contract(off)
    const int i = start + blockIdx.x * blockDim.x + threadIdx.x;
    if (i >= n_per_t) return;

    float mem = 0.f, spike = 0.f;
    #pragma unroll
    for (int t = 0; t < LIF_T; ++t) {
        mem   = (mem - spike) * LIF_DECAY + x[t * n_per_t + i];
        spike = rintf(fminf(fmaxf(mem, 0.f), 4.f));
        out[t * n_per_t + i] = spike;
    }
}

extern "C" void kernel_launch(void* const* d_in, const int* in_sizes, int n_in,
                              void* d_out, int out_size, void* d_ws, size_t ws_size,
                              hipStream_t stream)
{
    const float* x   = (const float*)d_in[0];
    float*       out = (float*)d_out;

    const int n_total   = in_sizes[0];        // T * N elements
    const int n_per_t   = n_total / LIF_T;    // spatial elements per timestep
    const int n4        = n_per_t / 4;        // float4 chunks per timestep
    const int nchunks   = n_total / 4;        // float4 chunks in whole tensor

    const int block = 256;

    // Probe 1: flat copy of the whole tensor (dst overwritten later).
    {
        int grid = (nchunks + block - 1) / block;
        if (grid > 2048) grid = 2048;
        zz_probe_flat_copy<<<grid, block, 0, stream>>>(
            (const float4*)x, (float4*)out, nchunks);
    }

    // Probe 2: 16-stream copy in the LIF pattern (dst overwritten later).
    if (n4 > 0) {
        const int grid = (n4 + block - 1) / block;
        zz_probe_8stream_copy<<<grid, block, 0, stream>>>(
            (const float4*)x, (float4*)out, n4);
    }

    // Correct scan — must run LAST so d_out is correct.
    if (n4 > 0) {
        const int grid = (n4 + block - 1) / block;   // 3136 blocks
        lif_kernel<<<grid, block, 0, stream>>>(
            (const float4*)x, (float4*)out, n4);
    }

    const int tail_start = n4 * 4;
    const int tail_n     = n_per_t - tail_start;
    if (tail_n > 0) {
        const int grid = (tail_n + 63) / 64;
        lif_kernel_tail<<<grid, 64, 0, stream>>>(x, out, n_per_t, tail_start);
    }
}